// Round 7
// baseline (902.522 us; speedup 1.0000x reference)
//
#include <hip/hip_runtime.h>
#include <math.h>

#define N_TOK 40
#define N1    41      // N_TOK + 1
#define BS    8
#define DD    256     // D
#define HH    256     // H
#define NTRI  10660   // C(41,3)
#define NPAIR 780     // pairs (i,k) with k-i>=2
#define NPTASK (NPAIR * BS)   // 6240 tasks, 16 lanes each
#define ROWF  (BS * N1 * HH)  // 83968 floats per [b][t][h] array
#define MNEG  (-1e38f)
#define DPB   256

// ---- MEASUREMENT ROUND: idempotent repeat factors so each phase's
// dispatch exceeds the ~40 µs fill cutoff and shows in the top-5 with its
// own dur_us + counters. phase_time = dur_us / REP. Outputs bit-identical
// (each repeat rewrites the same values).
#define PROJ_REP  16
#define SCORE_REP 6
#define DP_REP    4

// ---------------- Kernel 1: projections (R0 verbatim, repeated)
__global__ __launch_bounds__(256) void k_proj(
    const float* __restrict__ enc, const float* __restrict__ W1,
    const float* __restrict__ b1,
    float* __restrict__ P, float* __restrict__ Qb, float* __restrict__ Dd)
{
    const int t = blockIdx.x;    // 0..40
    const int h = threadIdx.x;   // 0..255
    __shared__ float e[BS][DD];

    for (int rep = 0; rep < PROJ_REP; ++rep) {
        #pragma unroll
        for (int b = 0; b < BS; ++b)
            e[b][h] = enc[(t * BS + b) * DD + h];
        __syncthreads();

        float accP[BS], accQ[BS];
        #pragma unroll
        for (int b = 0; b < BS; ++b) { accP[b] = 0.f; accQ[b] = 0.f; }

        for (int d = 0; d < DD; ++d) {
            float wp = W1[d * HH + h];
            float wq = W1[(DD + d) * HH + h];
            #pragma unroll
            for (int b = 0; b < BS; ++b) {
                float ev = e[b][d];
                accP[b] = fmaf(ev, wp, accP[b]);
                accQ[b] = fmaf(ev, wq, accQ[b]);
            }
        }
        float bb = b1[h];
        #pragma unroll
        for (int b = 0; b < BS; ++b) {
            int idx = ((b * N1) + t) * HH + h;
            P[idx]  = accP[b];
            Qb[idx] = accQ[b] + bb;
            Dd[idx] = accP[b] - accQ[b];
        }
        __syncthreads();
    }
}

// ---------------- Kernel 2: per-(i,k)-pair scores (R1 verbatim, repeated)
__global__ __launch_bounds__(256) void k_score(
    const float* __restrict__ P, const float* __restrict__ Qb,
    const float* __restrict__ Dd, const float* __restrict__ W2,
    const float* __restrict__ b2, float* __restrict__ S)
{
    const int gt   = blockIdx.x * 256 + threadIdx.x;
    const int task = gt >> 4;        // (pair, b), b fastest
    const int t    = gt & 15;

    const int p = task >> 3;         // pair index, w descending
    const int b = task & 7;

    int c = (int)((sqrtf(8.f * (float)p + 1.f) - 1.f) * 0.5f);
    while ((c + 1) * (c + 2) / 2 <= p) ++c;
    while (c * (c + 1) / 2 > p) --c;
    const int w    = 40 - c;
    const int i    = p - c * (c + 1) / 2;
    const int k    = i + w;
    const int nj   = w - 1;
    const int n2   = w - 2;
    const int base = n2 * (n2 + 1) * (119 - 2 * n2) / 6;   // == soff(w)

    const float4* Pr  = (const float4*)(P  + ((b * N1 + i) << 8)) + t * 4;
    const float4* Qr  = (const float4*)(Qb + ((b * N1 + k) << 8)) + t * 4;
    const float4* W2r = (const float4*)(W2) + t * 8;
    const float4* Drow0 = (const float4*)(Dd + ((b * N1 + i + 1) << 8)) + t * 4;
    float* Sout = S + b * NTRI + base + i * nj;

    for (int rep = 0; rep < SCORE_REP; ++rep) {
        float4 pp[4], qq[4], wa[4], wb[4];
        #pragma unroll
        for (int q = 0; q < 4; ++q) {
            pp[q] = Pr[q]; qq[q] = Qr[q];
            wa[q] = W2r[q * 2]; wb[q] = W2r[q * 2 + 1];
        }
        const float bb0 = b2[0], bb1 = b2[1];
        const float4* Drow = Drow0;

        for (int jp = 0; jp < nj; ++jp) {
            float s0 = 0.f, s1 = 0.f;
            #pragma unroll
            for (int q = 0; q < 4; ++q) {
                float4 dd = Drow[q];
                float r0 = fmaxf(dd.x + qq[q].x - pp[q].x, 0.f);
                float r1 = fmaxf(dd.y + qq[q].y - pp[q].y, 0.f);
                float r2 = fmaxf(dd.z + qq[q].z - pp[q].z, 0.f);
                float r3 = fmaxf(dd.w + qq[q].w - pp[q].w, 0.f);
                s0 = fmaf(r0, wa[q].x, s0); s1 = fmaf(r0, wa[q].y, s1);
                s0 = fmaf(r1, wa[q].z, s0); s1 = fmaf(r1, wa[q].w, s1);
                s0 = fmaf(r2, wb[q].x, s0); s1 = fmaf(r2, wb[q].y, s1);
                s0 = fmaf(r3, wb[q].z, s0); s1 = fmaf(r3, wb[q].w, s1);
            }
            #pragma unroll
            for (int d = 1; d < 16; d <<= 1) {
                s0 += __shfl_xor(s0, d);
                s1 += __shfl_xor(s1, d);
            }
            if (t == 0) {
                float S0 = s0 + bb0, S1 = s1 + bb1;
                Sout[jp] = fmaxf(S0, S1) + log1pf(__expf(-fabsf(S0 - S1)));
            }
            Drow += 64;
        }
    }
}

// ---------------- Kernel 3: per-batch DP (R0 verbatim, repeated)
__device__ __forceinline__ int tri_base(int i) { return (i * (81 - i)) >> 1; }
#define BIDX(i, j) (tri_base(i) + ((j) - (i) - 1))

constexpr int soff(int W) {
    int s = 0;
    for (int v = 2; v < W; ++v) s += (N1 - v) * (v - 1);
    return s;
}
constexpr int pick_T(int m, int nj) {
    int T = 1;
    while (T < 16 && m * (T * 2) <= DPB && T < nj) T *= 2;
    return T;
}

template<int W>
__device__ __forceinline__ void dp_step(float* __restrict__ Btri,
                                        const float* __restrict__ Sl, int tid)
{
    constexpr int m    = N1 - W;
    constexpr int nj   = W - 1;
    constexpr int T    = pick_T(m, nj);
    constexpr int CH   = (nj + T - 1) / T;
    constexpr int base = soff(W);

    if (tid < m * T) {
        const int i = tid / T;
        const int h = tid % T;
        const int k = i + W;

        float g[CH];
        #pragma unroll
        for (int q = 0; q < CH; ++q) {
            int jp = h + q * T;
            bool live = (q < CH - 1) || (jp < nj);
            int jj = live ? jp : 0;
            float v = Sl[base + i * nj + jj]
                    + Btri[BIDX(i, i + 1 + jj)]
                    + Btri[BIDX(i + 1 + jj, k)];
            g[q] = live ? v : MNEG;
        }
        float mx = g[0];
        #pragma unroll
        for (int q = 1; q < CH; ++q) mx = fmaxf(mx, g[q]);
        float s = 0.f;
        #pragma unroll
        for (int q = 0; q < CH; ++q) s += __expf(g[q] - mx);
        #pragma unroll
        for (int d = 1; d < T; d <<= 1) {
            float mo = __shfl_xor(mx, d);
            float so = __shfl_xor(s, d);
            float nm = fmaxf(mx, mo);
            s = s * __expf(mx - nm) + so * __expf(mo - nm);
            mx = nm;
        }
        if (h == 0)
            Btri[BIDX(i, k)] = mx + __logf(s);
    }
    __syncthreads();
}

template<int W>
__device__ __forceinline__ void dp_from(float* __restrict__ Btri,
                                        const float* __restrict__ Sl, int tid)
{
    dp_step<W>(Btri, Sl, tid);
    if constexpr (W + 1 <= N_TOK) dp_from<W + 1>(Btri, Sl, tid);
}

__global__ __launch_bounds__(DPB) void k_dp(
    const float* __restrict__ Sg, const int* __restrict__ lengths,
    float* __restrict__ out)
{
    __shared__ __align__(16) float Sl[NTRI];
    __shared__ float Btri[820];
    const int tid = threadIdx.x;
    const int b   = blockIdx.x;

    for (int rep = 0; rep < DP_REP; ++rep) {
        const float4* src = (const float4*)(Sg + b * NTRI);
        float4* dst = (float4*)Sl;
        for (int x = tid; x < NTRI / 4; x += DPB) dst[x] = src[x];
        if (tid < N_TOK) Btri[tri_base(tid)] = 0.f;
        __syncthreads();

        dp_from<2>(Btri, Sl, tid);

        if (tid == 0) {
            int L = lengths[b];
            out[b] = Btri[BIDX(0, L)];
        }
        __syncthreads();
    }
}

extern "C" void kernel_launch(void* const* d_in, const int* in_sizes, int n_in,
                              void* d_out, int out_size, void* d_ws, size_t ws_size,
                              hipStream_t stream)
{
    const float* enc = (const float*)d_in[0];
    const float* W1  = (const float*)d_in[1];
    const float* b1  = (const float*)d_in[2];
    const float* W2  = (const float*)d_in[3];
    const float* b2  = (const float*)d_in[4];
    const int* lengths = (const int*)d_in[5];

    float* ws = (float*)d_ws;
    float* P  = ws;
    float* Qb = ws + ROWF;
    float* Dd = ws + 2 * ROWF;
    float* S  = ws + 3 * ROWF;

    k_proj<<<dim3(N1), dim3(256), 0, stream>>>(enc, W1, b1, P, Qb, Dd);
    k_score<<<dim3(NPTASK * 16 / 256), dim3(256), 0, stream>>>(P, Qb, Dd, W2, b2, S);
    k_dp<<<dim3(BS), dim3(DPB), 0, stream>>>(S, lengths, (float*)d_out);
}

// Round 8
// 145.667 us; speedup vs baseline: 6.1958x; 6.1958x over previous
//
#include <hip/hip_runtime.h>
#include <math.h>

#define N_TOK 40
#define N1    41      // N_TOK + 1
#define BS    8
#define DD    256     // D
#define HH    256     // H
#define NTRI  10660   // C(41,3)
#define NPAIR 780     // pairs (i,k) with k-i>=2
#define NPTASK (NPAIR * BS)   // 6240 tasks, 16 lanes each
#define ROWF  (BS * N1 * HH)  // 83968 floats per [b][t][h] array
#define MNEG  (-1e38f)
#define DPB   256

// ---------------- Kernel 1: projections, latency-pipelined.
// Same math as R0 (per-(b,t,h) ascending-d fmaf chain, verbatim values) but:
//  (a) W1 loads ping-pong prefetched in 16-d register groups — group g+1's
//      32 loads issue BEFORE group g's 256 FMAs (full unroll: all indices
//      compile-time -> registers, no scratch).
//  (b) enc staged TRANSPOSED in LDS (et[d][b]) so the 8 per-d broadcast
//      b32 reads become 2 uniform-address b128 reads.
// R7 measured the old loop at ~375 cyc/iter (one naked L2 round-trip per d,
// VALUBusy 2.5%, 1 wave/SIMD). This structure hides load latency under the
// FMA block. Outputs bitwise identical.
__global__ __launch_bounds__(256) void k_proj(
    const float* __restrict__ enc, const float* __restrict__ W1,
    const float* __restrict__ b1,
    float* __restrict__ P, float* __restrict__ Qb, float* __restrict__ Dd)
{
    const int t = blockIdx.x;    // 0..40
    const int h = threadIdx.x;   // 0..255
    __shared__ __align__(16) float et[DD][BS];   // transposed: et[d][b], 8 KB

    // stage enc rows transposed (reads coalesced per b; one-time write cost)
    #pragma unroll
    for (int b = 0; b < BS; ++b)
        et[h][b] = enc[(t * BS + b) * DD + h];
    __syncthreads();

    float accP[BS], accQ[BS];
    #pragma unroll
    for (int b = 0; b < BS; ++b) { accP[b] = 0.f; accQ[b] = 0.f; }

    const float* Wp = W1 + h;              // W1[d*HH + h]
    const float* Wq = W1 + DD * HH + h;    // W1[(DD+d)*HH + h]

    float wp[2][16], wq[2][16];
    #pragma unroll
    for (int u = 0; u < 16; ++u) {         // prologue: group 0
        wp[0][u] = Wp[u * HH];
        wq[0][u] = Wq[u * HH];
    }

    #pragma unroll
    for (int g = 0; g < 16; ++g) {         // FULL unroll: cur/nxt/u static
        const int cur = g & 1, nxt = cur ^ 1;
        if (g < 15) {
            #pragma unroll
            for (int u = 0; u < 16; ++u) { // prefetch group g+1 (32 loads in flight)
                const int d = (g + 1) * 16 + u;
                wp[nxt][u] = Wp[d * HH];
                wq[nxt][u] = Wq[d * HH];
            }
        }
        #pragma unroll
        for (int u = 0; u < 16; ++u) {     // compute group g
            const int d = g * 16 + u;
            const float4 e03 = *(const float4*)&et[d][0];
            const float4 e47 = *(const float4*)&et[d][4];
            const float w0 = wp[cur][u], w1 = wq[cur][u];
            accP[0] = fmaf(e03.x, w0, accP[0]); accQ[0] = fmaf(e03.x, w1, accQ[0]);
            accP[1] = fmaf(e03.y, w0, accP[1]); accQ[1] = fmaf(e03.y, w1, accQ[1]);
            accP[2] = fmaf(e03.z, w0, accP[2]); accQ[2] = fmaf(e03.z, w1, accQ[2]);
            accP[3] = fmaf(e03.w, w0, accP[3]); accQ[3] = fmaf(e03.w, w1, accQ[3]);
            accP[4] = fmaf(e47.x, w0, accP[4]); accQ[4] = fmaf(e47.x, w1, accQ[4]);
            accP[5] = fmaf(e47.y, w0, accP[5]); accQ[5] = fmaf(e47.y, w1, accQ[5]);
            accP[6] = fmaf(e47.z, w0, accP[6]); accQ[6] = fmaf(e47.z, w1, accQ[6]);
            accP[7] = fmaf(e47.w, w0, accP[7]); accQ[7] = fmaf(e47.w, w1, accQ[7]);
        }
    }

    float bb = b1[h];
    #pragma unroll
    for (int b = 0; b < BS; ++b) {
        int idx = ((b * N1) + t) * HH + h;
        P[idx]  = accP[b];
        Qb[idx] = accQ[b] + bb;
        Dd[idx] = accP[b] - accQ[b];
    }
}

// ---------------- Kernel 2: per-(i,k)-pair scores (R1 verbatim)
__global__ __launch_bounds__(256) void k_score(
    const float* __restrict__ P, const float* __restrict__ Qb,
    const float* __restrict__ Dd, const float* __restrict__ W2,
    const float* __restrict__ b2, float* __restrict__ S)
{
    const int gt   = blockIdx.x * 256 + threadIdx.x;
    const int task = gt >> 4;        // (pair, b), b fastest
    const int t    = gt & 15;

    const int p = task >> 3;         // pair index, w descending
    const int b = task & 7;

    int c = (int)((sqrtf(8.f * (float)p + 1.f) - 1.f) * 0.5f);
    while ((c + 1) * (c + 2) / 2 <= p) ++c;
    while (c * (c + 1) / 2 > p) --c;
    const int w    = 40 - c;
    const int i    = p - c * (c + 1) / 2;
    const int k    = i + w;
    const int nj   = w - 1;
    const int n2   = w - 2;
    const int base = n2 * (n2 + 1) * (119 - 2 * n2) / 6;   // == soff(w)

    const float4* Pr  = (const float4*)(P  + ((b * N1 + i) << 8)) + t * 4;
    const float4* Qr  = (const float4*)(Qb + ((b * N1 + k) << 8)) + t * 4;
    const float4* W2r = (const float4*)(W2) + t * 8;

    float4 pp[4], qq[4], wa[4], wb[4];
    #pragma unroll
    for (int q = 0; q < 4; ++q) {
        pp[q] = Pr[q]; qq[q] = Qr[q];
        wa[q] = W2r[q * 2]; wb[q] = W2r[q * 2 + 1];
    }
    const float bb0 = b2[0], bb1 = b2[1];

    const float4* Drow = (const float4*)(Dd + ((b * N1 + i + 1) << 8)) + t * 4;
    float* Sout = S + b * NTRI + base + i * nj;

    for (int jp = 0; jp < nj; ++jp) {
        float s0 = 0.f, s1 = 0.f;
        #pragma unroll
        for (int q = 0; q < 4; ++q) {
            float4 dd = Drow[q];
            float r0 = fmaxf(dd.x + qq[q].x - pp[q].x, 0.f);
            float r1 = fmaxf(dd.y + qq[q].y - pp[q].y, 0.f);
            float r2 = fmaxf(dd.z + qq[q].z - pp[q].z, 0.f);
            float r3 = fmaxf(dd.w + qq[q].w - pp[q].w, 0.f);
            s0 = fmaf(r0, wa[q].x, s0); s1 = fmaf(r0, wa[q].y, s1);
            s0 = fmaf(r1, wa[q].z, s0); s1 = fmaf(r1, wa[q].w, s1);
            s0 = fmaf(r2, wb[q].x, s0); s1 = fmaf(r2, wb[q].y, s1);
            s0 = fmaf(r3, wb[q].z, s0); s1 = fmaf(r3, wb[q].w, s1);
        }
        #pragma unroll
        for (int d = 1; d < 16; d <<= 1) {
            s0 += __shfl_xor(s0, d);
            s1 += __shfl_xor(s1, d);
        }
        if (t == 0) {
            float S0 = s0 + bb0, S1 = s1 + bb1;
            Sout[jp] = fmaxf(S0, S1) + log1pf(__expf(-fabsf(S0 - S1)));
        }
        Drow += 64;
    }
}

// ---------------- Kernel 3: per-batch DP (R0 verbatim)
__device__ __forceinline__ int tri_base(int i) { return (i * (81 - i)) >> 1; }
#define BIDX(i, j) (tri_base(i) + ((j) - (i) - 1))

constexpr int soff(int W) {
    int s = 0;
    for (int v = 2; v < W; ++v) s += (N1 - v) * (v - 1);
    return s;
}
constexpr int pick_T(int m, int nj) {
    int T = 1;
    while (T < 16 && m * (T * 2) <= DPB && T < nj) T *= 2;
    return T;
}

template<int W>
__device__ __forceinline__ void dp_step(float* __restrict__ Btri,
                                        const float* __restrict__ Sl, int tid)
{
    constexpr int m    = N1 - W;
    constexpr int nj   = W - 1;
    constexpr int T    = pick_T(m, nj);
    constexpr int CH   = (nj + T - 1) / T;
    constexpr int base = soff(W);

    if (tid < m * T) {
        const int i = tid / T;
        const int h = tid % T;
        const int k = i + W;

        float g[CH];
        #pragma unroll
        for (int q = 0; q < CH; ++q) {
            int jp = h + q * T;
            bool live = (q < CH - 1) || (jp < nj);
            int jj = live ? jp : 0;
            float v = Sl[base + i * nj + jj]
                    + Btri[BIDX(i, i + 1 + jj)]
                    + Btri[BIDX(i + 1 + jj, k)];
            g[q] = live ? v : MNEG;
        }
        float mx = g[0];
        #pragma unroll
        for (int q = 1; q < CH; ++q) mx = fmaxf(mx, g[q]);
        float s = 0.f;
        #pragma unroll
        for (int q = 0; q < CH; ++q) s += __expf(g[q] - mx);
        #pragma unroll
        for (int d = 1; d < T; d <<= 1) {
            float mo = __shfl_xor(mx, d);
            float so = __shfl_xor(s, d);
            float nm = fmaxf(mx, mo);
            s = s * __expf(mx - nm) + so * __expf(mo - nm);
            mx = nm;
        }
        if (h == 0)
            Btri[BIDX(i, k)] = mx + __logf(s);
    }
    __syncthreads();
}

template<int W>
__device__ __forceinline__ void dp_from(float* __restrict__ Btri,
                                        const float* __restrict__ Sl, int tid)
{
    dp_step<W>(Btri, Sl, tid);
    if constexpr (W + 1 <= N_TOK) dp_from<W + 1>(Btri, Sl, tid);
}

__global__ __launch_bounds__(DPB) void k_dp(
    const float* __restrict__ Sg, const int* __restrict__ lengths,
    float* __restrict__ out)
{
    __shared__ __align__(16) float Sl[NTRI];
    __shared__ float Btri[820];
    const int tid = threadIdx.x;
    const int b   = blockIdx.x;

    const float4* src = (const float4*)(Sg + b * NTRI);
    float4* dst = (float4*)Sl;
    for (int x = tid; x < NTRI / 4; x += DPB) dst[x] = src[x];
    if (tid < N_TOK) Btri[tri_base(tid)] = 0.f;
    __syncthreads();

    dp_from<2>(Btri, Sl, tid);

    if (tid == 0) {
        int L = lengths[b];
        out[b] = Btri[BIDX(0, L)];
    }
}

extern "C" void kernel_launch(void* const* d_in, const int* in_sizes, int n_in,
                              void* d_out, int out_size, void* d_ws, size_t ws_size,
                              hipStream_t stream)
{
    const float* enc = (const float*)d_in[0];
    const float* W1  = (const float*)d_in[1];
    const float* b1  = (const float*)d_in[2];
    const float* W2  = (const float*)d_in[3];
    const float* b2  = (const float*)d_in[4];
    const int* lengths = (const int*)d_in[5];

    float* ws = (float*)d_ws;
    float* P  = ws;
    float* Qb = ws + ROWF;
    float* Dd = ws + 2 * ROWF;
    float* S  = ws + 3 * ROWF;

    k_proj<<<dim3(N1), dim3(256), 0, stream>>>(enc, W1, b1, P, Qb, Dd);
    k_score<<<dim3(NPTASK * 16 / 256), dim3(256), 0, stream>>>(P, Qb, Dd, W2, b2, S);
    k_dp<<<dim3(BS), dim3(DPB), 0, stream>>>(S, lengths, (float*)d_out);
}

// Round 9
// 139.196 us; speedup vs baseline: 6.4838x; 1.0465x over previous
//
#include <hip/hip_runtime.h>
#include <math.h>

#define N_TOK 40
#define N1    41      // N_TOK + 1
#define BS    8
#define DD    256     // D
#define HH    256     // H
#define NTRI  10660   // C(41,3)
#define NPAIR 780     // pairs (i,k) with k-i>=2
#define NPTASK (NPAIR * BS)   // 6240 tasks, 16 lanes each
#define ROWF  (BS * N1 * HH)  // 83968 floats per [b][t][h] array
#define MNEG  (-1e38f)
#define DPB   256

// ---------------- Kernel 1: projections, TLP version.
// R7 measured the 256-thread proj at ~40 µs: 1 wave/SIMD, ~375 cyc/d-iter of
// naked load latency (VALUBusy 2.5%, Occupancy 1.9%). R8's ILP ping-pong was
// defeated by the scheduler (total unchanged). This version hides latency
// with THREADS instead: 1024 threads/block = 16 waves = 4+/SIMD; thread
// (pr = tid>>8, h = tid&255) owns b-pair {2pr, 2pr+1}. Per-(b,t,h) chain is
// the identical ascending-d fmaf chain -> P/Qb/Dd bitwise identical.
__global__ __launch_bounds__(1024) void k_proj(
    const float* __restrict__ enc, const float* __restrict__ W1,
    const float* __restrict__ b1v,
    float* __restrict__ P, float* __restrict__ Qb, float* __restrict__ Dd)
{
    const int t  = blockIdx.x;           // 0..40
    const int h  = threadIdx.x & 255;    // 0..255
    const int pr = threadIdx.x >> 8;     // 0..3: b-pair
    const int bA = 2 * pr, bB = 2 * pr + 1;

    __shared__ float e[BS][DD];          // 8 KB
    // stage: thread (pr,h) writes e[2pr][h], e[2pr+1][h] (coalesced reads)
    e[bA][h] = enc[(t * BS + bA) * DD + h];
    e[bB][h] = enc[(t * BS + bB) * DD + h];
    __syncthreads();

    float a0 = 0.f, c0 = 0.f, a1 = 0.f, c1 = 0.f;
    const float* Wp = W1 + h;            // W1[d*HH + h]
    const float* Wq = W1 + DD * HH + h;  // W1[(DD+d)*HH + h]

    #pragma unroll 8
    for (int d = 0; d < DD; ++d) {
        float wp = Wp[d * HH];           // wave: consecutive h -> coalesced
        float wq = Wq[d * HH];
        float e0 = e[bA][d];             // wave-uniform -> LDS broadcast
        float e1 = e[bB][d];
        a0 = fmaf(e0, wp, a0); c0 = fmaf(e0, wq, c0);
        a1 = fmaf(e1, wp, a1); c1 = fmaf(e1, wq, c1);
    }

    const float bb = b1v[h];
    const int iA = ((bA * N1) + t) * HH + h;
    const int iB = ((bB * N1) + t) * HH + h;
    P[iA]  = a0;          P[iB]  = a1;
    Qb[iA] = c0 + bb;     Qb[iB] = c1 + bb;
    Dd[iA] = a0 - c0;     Dd[iB] = a1 - c1;
}

// ---------------- Kernel 2: per-(i,k)-pair scores (R1 verbatim)
__global__ __launch_bounds__(256) void k_score(
    const float* __restrict__ P, const float* __restrict__ Qb,
    const float* __restrict__ Dd, const float* __restrict__ W2,
    const float* __restrict__ b2, float* __restrict__ S)
{
    const int gt   = blockIdx.x * 256 + threadIdx.x;
    const int task = gt >> 4;        // (pair, b), b fastest
    const int t    = gt & 15;

    const int p = task >> 3;         // pair index, w descending
    const int b = task & 7;

    int c = (int)((sqrtf(8.f * (float)p + 1.f) - 1.f) * 0.5f);
    while ((c + 1) * (c + 2) / 2 <= p) ++c;
    while (c * (c + 1) / 2 > p) --c;
    const int w    = 40 - c;
    const int i    = p - c * (c + 1) / 2;
    const int k    = i + w;
    const int nj   = w - 1;
    const int n2   = w - 2;
    const int base = n2 * (n2 + 1) * (119 - 2 * n2) / 6;   // == soff(w)

    const float4* Pr  = (const float4*)(P  + ((b * N1 + i) << 8)) + t * 4;
    const float4* Qr  = (const float4*)(Qb + ((b * N1 + k) << 8)) + t * 4;
    const float4* W2r = (const float4*)(W2) + t * 8;

    float4 pp[4], qq[4], wa[4], wb[4];
    #pragma unroll
    for (int q = 0; q < 4; ++q) {
        pp[q] = Pr[q]; qq[q] = Qr[q];
        wa[q] = W2r[q * 2]; wb[q] = W2r[q * 2 + 1];
    }
    const float bb0 = b2[0], bb1 = b2[1];

    const float4* Drow = (const float4*)(Dd + ((b * N1 + i + 1) << 8)) + t * 4;
    float* Sout = S + b * NTRI + base + i * nj;

    for (int jp = 0; jp < nj; ++jp) {
        float s0 = 0.f, s1 = 0.f;
        #pragma unroll
        for (int q = 0; q < 4; ++q) {
            float4 dd = Drow[q];
            float r0 = fmaxf(dd.x + qq[q].x - pp[q].x, 0.f);
            float r1 = fmaxf(dd.y + qq[q].y - pp[q].y, 0.f);
            float r2 = fmaxf(dd.z + qq[q].z - pp[q].z, 0.f);
            float r3 = fmaxf(dd.w + qq[q].w - pp[q].w, 0.f);
            s0 = fmaf(r0, wa[q].x, s0); s1 = fmaf(r0, wa[q].y, s1);
            s0 = fmaf(r1, wa[q].z, s0); s1 = fmaf(r1, wa[q].w, s1);
            s0 = fmaf(r2, wb[q].x, s0); s1 = fmaf(r2, wb[q].y, s1);
            s0 = fmaf(r3, wb[q].z, s0); s1 = fmaf(r3, wb[q].w, s1);
        }
        #pragma unroll
        for (int d = 1; d < 16; d <<= 1) {
            s0 += __shfl_xor(s0, d);
            s1 += __shfl_xor(s1, d);
        }
        if (t == 0) {
            float S0 = s0 + bb0, S1 = s1 + bb1;
            Sout[jp] = fmaxf(S0, S1) + log1pf(__expf(-fabsf(S0 - S1)));
        }
        Drow += 64;
    }
}

// ---------------- Kernel 3: per-batch DP (R0 verbatim)
__device__ __forceinline__ int tri_base(int i) { return (i * (81 - i)) >> 1; }
#define BIDX(i, j) (tri_base(i) + ((j) - (i) - 1))

constexpr int soff(int W) {
    int s = 0;
    for (int v = 2; v < W; ++v) s += (N1 - v) * (v - 1);
    return s;
}
constexpr int pick_T(int m, int nj) {
    int T = 1;
    while (T < 16 && m * (T * 2) <= DPB && T < nj) T *= 2;
    return T;
}

template<int W>
__device__ __forceinline__ void dp_step(float* __restrict__ Btri,
                                        const float* __restrict__ Sl, int tid)
{
    constexpr int m    = N1 - W;
    constexpr int nj   = W - 1;
    constexpr int T    = pick_T(m, nj);
    constexpr int CH   = (nj + T - 1) / T;
    constexpr int base = soff(W);

    if (tid < m * T) {
        const int i = tid / T;
        const int h = tid % T;
        const int k = i + W;

        float g[CH];
        #pragma unroll
        for (int q = 0; q < CH; ++q) {
            int jp = h + q * T;
            bool live = (q < CH - 1) || (jp < nj);
            int jj = live ? jp : 0;
            float v = Sl[base + i * nj + jj]
                    + Btri[BIDX(i, i + 1 + jj)]
                    + Btri[BIDX(i + 1 + jj, k)];
            g[q] = live ? v : MNEG;
        }
        float mx = g[0];
        #pragma unroll
        for (int q = 1; q < CH; ++q) mx = fmaxf(mx, g[q]);
        float s = 0.f;
        #pragma unroll
        for (int q = 0; q < CH; ++q) s += __expf(g[q] - mx);
        #pragma unroll
        for (int d = 1; d < T; d <<= 1) {
            float mo = __shfl_xor(mx, d);
            float so = __shfl_xor(s, d);
            float nm = fmaxf(mx, mo);
            s = s * __expf(mx - nm) + so * __expf(mo - nm);
            mx = nm;
        }
        if (h == 0)
            Btri[BIDX(i, k)] = mx + __logf(s);
    }
    __syncthreads();
}

template<int W>
__device__ __forceinline__ void dp_from(float* __restrict__ Btri,
                                        const float* __restrict__ Sl, int tid)
{
    dp_step<W>(Btri, Sl, tid);
    if constexpr (W + 1 <= N_TOK) dp_from<W + 1>(Btri, Sl, tid);
}

__global__ __launch_bounds__(DPB) void k_dp(
    const float* __restrict__ Sg, const int* __restrict__ lengths,
    float* __restrict__ out)
{
    __shared__ __align__(16) float Sl[NTRI];
    __shared__ float Btri[820];
    const int tid = threadIdx.x;
    const int b   = blockIdx.x;

    const float4* src = (const float4*)(Sg + b * NTRI);
    float4* dst = (float4*)Sl;
    for (int x = tid; x < NTRI / 4; x += DPB) dst[x] = src[x];
    if (tid < N_TOK) Btri[tri_base(tid)] = 0.f;
    __syncthreads();

    dp_from<2>(Btri, Sl, tid);

    if (tid == 0) {
        int L = lengths[b];
        out[b] = Btri[BIDX(0, L)];
    }
}

extern "C" void kernel_launch(void* const* d_in, const int* in_sizes, int n_in,
                              void* d_out, int out_size, void* d_ws, size_t ws_size,
                              hipStream_t stream)
{
    const float* enc = (const float*)d_in[0];
    const float* W1  = (const float*)d_in[1];
    const float* b1  = (const float*)d_in[2];
    const float* W2  = (const float*)d_in[3];
    const float* b2  = (const float*)d_in[4];
    const int* lengths = (const int*)d_in[5];

    float* ws = (float*)d_ws;
    float* P  = ws;
    float* Qb = ws + ROWF;
    float* Dd = ws + 2 * ROWF;
    float* S  = ws + 3 * ROWF;

    k_proj<<<dim3(N1), dim3(1024), 0, stream>>>(enc, W1, b1, P, Qb, Dd);
    k_score<<<dim3(NPTASK * 16 / 256), dim3(256), 0, stream>>>(P, Qb, Dd, W2, b2, S);
    k_dp<<<dim3(BS), dim3(DPB), 0, stream>>>(S, lengths, (float*)d_out);
}